// Round 8
// baseline (3192.253 us; speedup 1.0000x reference)
//
#include <hip/hip_runtime.h>

#define BB 256
#define TT 64
#define HH 512
#define CC 97
#define SS 26
#define KX 1024
#define GRIDN 256

typedef __attribute__((ext_vector_type(8))) short short8;
typedef __attribute__((ext_vector_type(4))) float f32x4;

#define MFMA16(a, b, c) __builtin_amdgcn_mfma_f32_16x16x32_bf16((a), (b), (c), 0, 0, 0)

__device__ __forceinline__ unsigned short f2bf(float x) {
  unsigned int u = __float_as_uint(x);
  u += 0x7FFFu + ((u >> 16) & 1u);
  return (unsigned short)(u >> 16);
}
__device__ __forceinline__ float bf2f(unsigned short b) {
  return __uint_as_float(((unsigned int)b) << 16);
}
__device__ __forceinline__ void split8(float4 a, float4 b, short8& vh, short8& vl) {
  float x[8] = {a.x, a.y, a.z, a.w, b.x, b.y, b.z, b.w};
#pragma unroll
  for (int i = 0; i < 8; ++i) {
    unsigned short h = f2bf(x[i]);
    vh[i] = (short)h;
    vl[i] = (short)f2bf(x[i] - bf2f(h));
  }
}

// software grid barrier: monotonic counter, device-scope atomics (XCD-coherent).
// Co-residency is capacity-guaranteed (256 blocks x 4 waves x 21KB LDS << chip).
__device__ __forceinline__ void gbar(unsigned* bar) {
  __syncthreads();
  if (threadIdx.x == 0) {
    __threadfence();  // release: drain block's stores to device scope
    unsigned t = atomicAdd(bar, 1u);
    unsigned target = (t / GRIDN + 1u) * GRIDN;
    while (atomicAdd(bar, 0u) < target) __builtin_amdgcn_s_sleep(2);
    __threadfence();  // acquire
  }
  __syncthreads();
}

// ---------------------------------------------------------------------------
__global__ __launch_bounds__(256) void k_init(float4* __restrict__ p, int n4) {
  int i = blockIdx.x * 256 + threadIdx.x;
  if (i < n4) p[i] = make_float4(0.f, 0.f, 0.f, 0.f);
}

// ---------------------------------------------------------------------------
// prep: pack W_ih[:, :512] | W_hh into Wp_hi/lo [2048][1024] bf16, packed row
// p = ntile*64 + q*16 + jlow  (j = ntile*16+jlow, gate row g = q*512 + j)
// ---------------------------------------------------------------------------
__global__ __launch_bounds__(256) void k_prep_wp(const float* __restrict__ W_ih, const float* __restrict__ b_ih,
                                                 const float* __restrict__ W_hh, const float* __restrict__ b_hh,
                                                 unsigned short* __restrict__ Wp_hi, unsigned short* __restrict__ Wp_lo,
                                                 float* __restrict__ bp2, float* __restrict__ Woh2) {
  int p = blockIdx.x;
  int ntile = p >> 6, q = (p >> 4) & 3, jl = p & 15;
  int g = q * 512 + ntile * 16 + jl;
  int tid = threadIdx.x;
  for (int k = tid; k < 1024; k += 256) {
    float v = (k < 512) ? W_ih[(size_t)g * 609 + k] : W_hh[(size_t)g * 512 + (k - 512)];
    unsigned short h = f2bf(v);
    Wp_hi[(size_t)p * 1024 + k] = h;
    Wp_lo[(size_t)p * 1024 + k] = f2bf(v - bf2f(h));
  }
  if (tid < CC) Woh2[(size_t)p * CC + tid] = W_ih[(size_t)g * 609 + 512 + tid];
  if (tid == 0) bp2[p] = b_ih[g] + b_hh[g];
}

__global__ __launch_bounds__(256) void k_prep_w2h(const float* __restrict__ W_h2h,
                                                  unsigned short* __restrict__ Whi, unsigned short* __restrict__ Wlo) {
  int n = blockIdx.x;
  int tid = threadIdx.x;
  for (int k = tid; k < 512; k += 256) {
    float v = W_h2h[(size_t)n * 512 + k];
    unsigned short h = f2bf(v);
    Whi[(size_t)n * 512 + k] = h;
    Wlo[(size_t)n * 512 + k] = f2bf(v - bf2f(h));
  }
}

// W_cls -> hi/lo bf16, padded to 112 rows (runs AFTER k_loop; aliases pp space)
__global__ __launch_bounds__(256) void k_prep_wc(const float* __restrict__ Wc,
                                                 unsigned short* __restrict__ Wc_hi, unsigned short* __restrict__ Wc_lo) {
  int n = blockIdx.x;  // 0..111
  int tid = threadIdx.x;
  for (int k = tid; k < 512; k += 256) {
    float v = (n < CC) ? Wc[(size_t)n * 512 + k] : 0.f;
    unsigned short h = f2bf(v);
    Wc_hi[(size_t)n * 512 + k] = h;
    Wc_lo[(size_t)n * 512 + k] = f2bf(v - bf2f(h));
  }
}

// ---------------------------------------------------------------------------
// K0: proj = bh @ W_i2h^T  (M=16384,N=512,K=512) hi/lo bf16 MFMA, out bf16.
// ---------------------------------------------------------------------------
__global__ __launch_bounds__(256) void k0_proj(const float* __restrict__ A, const float* __restrict__ Bw,
                                               unsigned short* __restrict__ projb) {
  __shared__ short Ah[128][40], Al[128][40], Bh[64][40], Bl[64][40];
  int mt = blockIdx.x >> 3, nt = blockIdx.x & 7;
  int m0 = mt * 128, n0 = nt * 64;
  int tid = threadIdx.x;
  int w = tid >> 6, l = tid & 63;
  int wm = w >> 1, wn = w & 1;
  f32x4 acc[4][2];
#pragma unroll
  for (int i = 0; i < 4; ++i)
#pragma unroll
    for (int j = 0; j < 2; ++j) acc[i][j] = (f32x4){0.f, 0.f, 0.f, 0.f};
  int ar_s = tid >> 1, akc = (tid & 1) * 16;
  int br_s = tid >> 2, bkc = (tid & 3) * 8;
  for (int k0 = 0; k0 < 512; k0 += 32) {
    {
      const float* s = &A[(size_t)(m0 + ar_s) * 512 + k0 + akc];
      short8 vh, vl;
      split8(*(const float4*)s, *(const float4*)(s + 4), vh, vl);
      *(short8*)&Ah[ar_s][akc] = vh; *(short8*)&Al[ar_s][akc] = vl;
      split8(*(const float4*)(s + 8), *(const float4*)(s + 12), vh, vl);
      *(short8*)&Ah[ar_s][akc + 8] = vh; *(short8*)&Al[ar_s][akc + 8] = vl;
      const float* sb = &Bw[(size_t)(n0 + br_s) * 512 + k0 + bkc];
      split8(*(const float4*)sb, *(const float4*)(sb + 4), vh, vl);
      *(short8*)&Bh[br_s][bkc] = vh; *(short8*)&Bl[br_s][bkc] = vl;
    }
    __syncthreads();
    int ko = (l >> 4) * 8;
    short8 ah[4], al8[4];
#pragma unroll
    for (int mf = 0; mf < 4; ++mf) {
      int ar = wm * 64 + mf * 16 + (l & 15);
      ah[mf] = *(short8*)&Ah[ar][ko];
      al8[mf] = *(short8*)&Al[ar][ko];
    }
#pragma unroll
    for (int nf = 0; nf < 2; ++nf) {
      int br = wn * 32 + nf * 16 + (l & 15);
      short8 bh8 = *(short8*)&Bh[br][ko];
      short8 bl8 = *(short8*)&Bl[br][ko];
#pragma unroll
      for (int mf = 0; mf < 4; ++mf) {
        acc[mf][nf] = MFMA16(ah[mf], bh8, acc[mf][nf]);
        acc[mf][nf] = MFMA16(ah[mf], bl8, acc[mf][nf]);
        acc[mf][nf] = MFMA16(al8[mf], bh8, acc[mf][nf]);
      }
    }
    __syncthreads();
  }
#pragma unroll
  for (int mf = 0; mf < 4; ++mf)
#pragma unroll
    for (int nf = 0; nf < 2; ++nf)
#pragma unroll
      for (int r = 0; r < 4; ++r) {
        int m = m0 + wm * 64 + mf * 16 + (l >> 4) * 4 + r;
        int n = n0 + wn * 32 + nf * 16 + (l & 15);
        projb[(size_t)m * 512 + n] = f2bf(acc[mf][nf][r]);
      }
}

// ---------------------------------------------------------------------------
// k_loop: 26-step recurrence, ONE plain kernel, software grid barrier.
// grid 256 x 256. Per step:
//   P1 (blocks 0..31): pp = h @ W_h2h^T, 64x64 tile, full K=512 (round-1 k1)
//   P2 (all 256): per-b attention score->softmax->ctx (round-4 phase2, pp single)
//   P3 (blocks 0..127): gates MFMA + fused LSTM (round-1 k3)
// ---------------------------------------------------------------------------
__global__ __launch_bounds__(256) void k_loop(
    const unsigned short* __restrict__ projb,
    const unsigned short* __restrict__ W2h_hi, const unsigned short* __restrict__ W2h_lo,
    const unsigned short* __restrict__ Wp_hi, const unsigned short* __restrict__ Wp_lo,
    const float* __restrict__ bp2, const float* __restrict__ Woh2,
    const float* __restrict__ b_h2h, const float* __restrict__ w_score,
    const float* __restrict__ bh, const int* __restrict__ ctxids,
    float* __restrict__ xA, float* __restrict__ xB, float* __restrict__ cbuf,
    float* __restrict__ pp, float* __restrict__ hsb, unsigned* __restrict__ bar) {
  __shared__ short Ah[64][40], Al[64][40], Bh[64][40], Bl[64][40];
  __shared__ float sc_s[64];
  __shared__ int cid_s[64];
  int bid = blockIdx.x, tid = threadIdx.x;
  int w = tid >> 6, l = tid & 63;

  for (int s = 0; s < SS; ++s) {
    float* xc = (s & 1) ? xB : xA;
    float* xn = (s & 1) ? xA : xB;

    // ---------------- P1: pp = h @ W2h^T (blocks 0..31) ----------------
    if (bid < 32) {
      int bt = bid & 3, nt = bid >> 2;
      int b0 = bt * 64, n0 = nt * 64;
      int wm = w >> 1, wn = w & 1;
      f32x4 acc[2][2];
#pragma unroll
      for (int i = 0; i < 2; ++i)
#pragma unroll
        for (int j = 0; j < 2; ++j) acc[i][j] = (f32x4){0.f, 0.f, 0.f, 0.f};
      int row = tid >> 2, kc = (tid & 3) * 8;
      for (int k0 = 0; k0 < 512; k0 += 32) {
        {
          const float* sp = &xc[(size_t)(b0 + row) * KX + 512 + k0 + kc];
          short8 vh, vl;
          split8(*(const float4*)sp, *(const float4*)(sp + 4), vh, vl);
          *(short8*)&Ah[row][kc] = vh; *(short8*)&Al[row][kc] = vl;
          *(short8*)&Bh[row][kc] = *(const short8*)&W2h_hi[(size_t)(n0 + row) * 512 + k0 + kc];
          *(short8*)&Bl[row][kc] = *(const short8*)&W2h_lo[(size_t)(n0 + row) * 512 + k0 + kc];
        }
        __syncthreads();
        int ko = (l >> 4) * 8;
        short8 ah[2], al8[2];
#pragma unroll
        for (int mf = 0; mf < 2; ++mf) {
          int ar = wm * 32 + mf * 16 + (l & 15);
          ah[mf] = *(short8*)&Ah[ar][ko];
          al8[mf] = *(short8*)&Al[ar][ko];
        }
#pragma unroll
        for (int nf = 0; nf < 2; ++nf) {
          int br = wn * 32 + nf * 16 + (l & 15);
          short8 bh8 = *(short8*)&Bh[br][ko];
          short8 bl8 = *(short8*)&Bl[br][ko];
#pragma unroll
          for (int mf = 0; mf < 2; ++mf) {
            acc[mf][nf] = MFMA16(ah[mf], bh8, acc[mf][nf]);
            acc[mf][nf] = MFMA16(ah[mf], bl8, acc[mf][nf]);
            acc[mf][nf] = MFMA16(al8[mf], bh8, acc[mf][nf]);
          }
        }
        __syncthreads();
      }
#pragma unroll
      for (int mf = 0; mf < 2; ++mf)
#pragma unroll
        for (int nf = 0; nf < 2; ++nf)
#pragma unroll
          for (int r = 0; r < 4; ++r) {
            int m = b0 + wm * 32 + mf * 16 + (l >> 4) * 4 + r;
            int n = n0 + wn * 32 + nf * 16 + (l & 15);
            pp[(size_t)m * HH + n] = acc[mf][nf][r];
          }
    }
    gbar(bar);

    // ---------------- P2: attention (block b = bid) ----------------
    {
      int b = bid;
      float ppv[8], svv[8];
      {
        int l8 = l * 8;
        const float* p0 = &pp[(size_t)b * HH + l8];
        float4 a0 = *(const float4*)p0, a1 = *(const float4*)(p0 + 4);
        float4 c0 = *(const float4*)&b_h2h[l8], c1 = *(const float4*)&b_h2h[l8 + 4];
        float4 d0 = *(const float4*)&w_score[l8], d1 = *(const float4*)&w_score[l8 + 4];
        ppv[0] = a0.x + c0.x; ppv[1] = a0.y + c0.y; ppv[2] = a0.z + c0.z; ppv[3] = a0.w + c0.w;
        ppv[4] = a1.x + c1.x; ppv[5] = a1.y + c1.y; ppv[6] = a1.z + c1.z; ppv[7] = a1.w + c1.w;
        svv[0] = d0.x; svv[1] = d0.y; svv[2] = d0.z; svv[3] = d0.w;
        svv[4] = d1.x; svv[5] = d1.y; svv[6] = d1.z; svv[7] = d1.w;
      }
      for (int t = w; t < 64; t += 4) {
        const unsigned short* pr = &projb[((size_t)b * 64 + t) * 512 + l * 8];
        uint4 raw = *(const uint4*)pr;
        unsigned int uu[4] = {raw.x, raw.y, raw.z, raw.w};
        float acc = 0.f;
#pragma unroll
        for (int i = 0; i < 4; ++i) {
          float f0 = bf2f((unsigned short)(uu[i] & 0xFFFFu));
          float f1 = bf2f((unsigned short)(uu[i] >> 16));
          acc += tanhf(f0 + ppv[2 * i]) * svv[2 * i];
          acc += tanhf(f1 + ppv[2 * i + 1]) * svv[2 * i + 1];
        }
#pragma unroll
        for (int off = 32; off > 0; off >>= 1) acc += __shfl_down(acc, off);
        if (l == 0) sc_s[t] = acc;
      }
      __syncthreads();
      if (w == 0) {
        float x = sc_s[l];
        float m = x;
#pragma unroll
        for (int off = 32; off > 0; off >>= 1) m = fmaxf(m, __shfl_xor(m, off));
        float e = __expf(x - m);
        float ssum = e;
#pragma unroll
        for (int off = 32; off > 0; off >>= 1) ssum += __shfl_xor(ssum, off);
        sc_s[l] = e / ssum;
      }
      __syncthreads();
      float a0 = 0.f, a1 = 0.f;
      for (int t = 0; t < 64; ++t) {
        float wgt = sc_s[t];
        const float* pb = &bh[((size_t)b * 64 + t) * 512];
        a0 += wgt * pb[tid];
        a1 += wgt * pb[tid + 256];
      }
      xc[(size_t)b * KX + tid] = a0;
      xc[(size_t)b * KX + tid + 256] = a1;
    }
    gbar(bar);

    // ---------------- P3: gates + LSTM (blocks 0..127) ----------------
    if (bid < 128) {
      int bt = bid & 3, ntile = bid >> 2;
      int b0 = bt * 64, n0 = ntile * 64, jb = ntile * 16;
      if (tid < 64) cid_s[tid] = ctxids[(size_t)(b0 + tid) * SS + s];
      f32x4 acc[4];
#pragma unroll
      for (int i = 0; i < 4; ++i) acc[i] = (f32x4){0.f, 0.f, 0.f, 0.f};
      int row = tid >> 2, kc = (tid & 3) * 8;
      for (int k0 = 0; k0 < 1024; k0 += 32) {
        {
          const float* sp = &xc[(size_t)(b0 + row) * KX + k0 + kc];
          short8 vh, vl;
          split8(*(const float4*)sp, *(const float4*)(sp + 4), vh, vl);
          *(short8*)&Ah[row][kc] = vh; *(short8*)&Al[row][kc] = vl;
          *(short8*)&Bh[row][kc] = *(const short8*)&Wp_hi[(size_t)(n0 + row) * 1024 + k0 + kc];
          *(short8*)&Bl[row][kc] = *(const short8*)&Wp_lo[(size_t)(n0 + row) * 1024 + k0 + kc];
        }
        __syncthreads();
        int ko = (l >> 4) * 8;
        int ar = w * 16 + (l & 15);
        short8 ah = *(short8*)&Ah[ar][ko];
        short8 al8 = *(short8*)&Al[ar][ko];
#pragma unroll
        for (int nf = 0; nf < 4; ++nf) {
          int br = nf * 16 + (l & 15);
          short8 bh8 = *(short8*)&Bh[br][ko];
          short8 bl8 = *(short8*)&Bl[br][ko];
          acc[nf] = MFMA16(ah, bh8, acc[nf]);
          acc[nf] = MFMA16(ah, bl8, acc[nf]);
          acc[nf] = MFMA16(al8, bh8, acc[nf]);
        }
        __syncthreads();
      }
      int jl = l & 15, j = jb + jl;
      float bia[4];
#pragma unroll
      for (int q = 0; q < 4; ++q) bia[q] = bp2[n0 + q * 16 + jl];
#pragma unroll
      for (int r = 0; r < 4; ++r) {
        int br_ = b0 + w * 16 + (l >> 4) * 4 + r;
        int cid = cid_s[w * 16 + (l >> 4) * 4 + r];
        float gi = acc[0][r] + bia[0] + Woh2[(size_t)(n0 + 0 + jl) * CC + cid];
        float gf = acc[1][r] + bia[1] + Woh2[(size_t)(n0 + 16 + jl) * CC + cid];
        float gg = acc[2][r] + bia[2] + Woh2[(size_t)(n0 + 32 + jl) * CC + cid];
        float go = acc[3][r] + bia[3] + Woh2[(size_t)(n0 + 48 + jl) * CC + cid];
        float iv = 1.f / (1.f + __expf(-gi));
        float fv = 1.f / (1.f + __expf(-gf));
        float gv = tanhf(gg);
        float ov = 1.f / (1.f + __expf(-go));
        float cNew = fv * cbuf[(size_t)br_ * HH + j] + iv * gv;
        cbuf[(size_t)br_ * HH + j] = cNew;
        float hv = ov * tanhf(cNew);
        xn[(size_t)br_ * KX + 512 + j] = hv;
        hsb[((size_t)br_ * SS + s) * HH + j] = hv;
      }
    }
    gbar(bar);
  }
}

// ---------------------------------------------------------------------------
// K4: probs = hs @ W_cls^T + b_cls via hi/lo MFMA. M=6656, N=112(pad 97), K=512.
// ---------------------------------------------------------------------------
__global__ __launch_bounds__(256) void k4_cls(const float* __restrict__ hsb,
                                              const unsigned short* __restrict__ Wc_hi,
                                              const unsigned short* __restrict__ Wc_lo,
                                              const float* __restrict__ bc, float* __restrict__ out) {
  __shared__ short Ah[64][40], Al[64][40];
  __shared__ short Bh[112][40], Bl[112][40];
  int m0 = blockIdx.x * 64;
  int tid = threadIdx.x, w = tid >> 6, l = tid & 63;
  f32x4 acc[7];
#pragma unroll
  for (int i = 0; i < 7; ++i) acc[i] = (f32x4){0.f, 0.f, 0.f, 0.f};
  int row = tid >> 2, kc = (tid & 3) * 8;
  for (int k0 = 0; k0 < 512; k0 += 32) {
    {
      const float* sp = &hsb[(size_t)(m0 + row) * 512 + k0 + kc];
      short8 vh, vl;
      split8(*(const float4*)sp, *(const float4*)(sp + 4), vh, vl);
      *(short8*)&Ah[row][kc] = vh; *(short8*)&Al[row][kc] = vl;
    }
    for (int i = tid; i < 448; i += 256) {
      int r = i >> 2, kb = (i & 3) * 8;
      *(short8*)&Bh[r][kb] = *(const short8*)&Wc_hi[(size_t)r * 512 + k0 + kb];
      *(short8*)&Bl[r][kb] = *(const short8*)&Wc_lo[(size_t)r * 512 + k0 + kb];
    }
    __syncthreads();
    int ko = (l >> 4) * 8;
    short8 ah = *(short8*)&Ah[w * 16 + (l & 15)][ko];
    short8 al8 = *(short8*)&Al[w * 16 + (l & 15)][ko];
#pragma unroll
    for (int nf = 0; nf < 7; ++nf) {
      short8 bh8 = *(short8*)&Bh[nf * 16 + (l & 15)][ko];
      short8 bl8 = *(short8*)&Bl[nf * 16 + (l & 15)][ko];
      acc[nf] = MFMA16(ah, bh8, acc[nf]);
      acc[nf] = MFMA16(ah, bl8, acc[nf]);
      acc[nf] = MFMA16(al8, bh8, acc[nf]);
    }
    __syncthreads();
  }
#pragma unroll
  for (int nf = 0; nf < 7; ++nf)
#pragma unroll
    for (int r = 0; r < 4; ++r) {
      int m = m0 + w * 16 + (l >> 4) * 4 + r;
      int n = nf * 16 + (l & 15);
      if (n < CC) out[(size_t)m * CC + n] = acc[nf][r] + bc[n];
    }
}

// ---------------------------------------------------------------------------
extern "C" void kernel_launch(void* const* d_in, const int* in_sizes, int n_in,
                              void* d_out, int out_size, void* d_ws, size_t ws_size,
                              hipStream_t stream) {
  const float* bh      = (const float*)d_in[0];   // [256,64,512]
  const int*   ctxi    = (const int*)d_in[1];     // [256,26]
  const float* W_i2h   = (const float*)d_in[4];   // [512,512]
  const float* W_h2h   = (const float*)d_in[5];   // [512,512]
  const float* b_h2h   = (const float*)d_in[6];   // [512]
  const float* w_score = (const float*)d_in[7];   // [1,512]
  const float* W_ih    = (const float*)d_in[8];   // [2048,609]
  const float* b_ih    = (const float*)d_in[9];   // [2048]
  const float* W_hh    = (const float*)d_in[10];  // [2048,512]
  const float* b_hh    = (const float*)d_in[11];  // [2048]
  const float* W_cls   = (const float*)d_in[12];  // [97,512]
  const float* b_cls   = (const float*)d_in[13];  // [97]
  float* out = (float*)d_out;

  // workspace layout (~41.8 MB, matches round-4-proven footprint)
  float* xA   = (float*)d_ws;                       // [256][1024]
  float* xB   = xA + (size_t)BB * KX;               // [256][1024]
  float* cbuf = xB + (size_t)BB * KX;               // [256][512]
  unsigned* bar = (unsigned*)(cbuf + (size_t)BB * HH);  // 64 floats reserved
  float* pp   = (float*)bar + 64;                   // [256][512]
  float* hsb  = pp + (size_t)BB * HH;               // [256][26][512]
  unsigned short* projb  = (unsigned short*)(hsb + (size_t)BB * SS * HH);  // [16384][512] bf16
  unsigned short* Wp_hi  = projb + (size_t)16384 * 512;                    // [2048][1024] bf16
  unsigned short* Wp_lo  = Wp_hi + (size_t)2048 * 1024;
  unsigned short* W2h_hi = Wp_lo + (size_t)2048 * 1024;                    // [512][512] bf16
  unsigned short* W2h_lo = W2h_hi + (size_t)512 * 512;
  float* bp2  = (float*)(W2h_lo + (size_t)512 * 512);                      // [2048]
  float* Woh2 = bp2 + 2048;                                                // [2048][97]
  // Wc aliases pp's space (pp dead after k_loop; prep_wc runs after k_loop)
  unsigned short* Wc_hi = (unsigned short*)pp;                             // [112][512] bf16
  unsigned short* Wc_lo = Wc_hi + (size_t)112 * 512;

  // zero xA, xB, cbuf, bar: 655424 floats = 163856 float4
  k_init<<<dim3(641), dim3(256), 0, stream>>>((float4*)d_ws, 163856);
  k_prep_wp<<<dim3(2048), dim3(256), 0, stream>>>(W_ih, b_ih, W_hh, b_hh, Wp_hi, Wp_lo, bp2, Woh2);
  k_prep_w2h<<<dim3(512), dim3(256), 0, stream>>>(W_h2h, W2h_hi, W2h_lo);
  k0_proj<<<dim3(1024), dim3(256), 0, stream>>>(bh, W_i2h, projb);

  k_loop<<<dim3(GRIDN), dim3(256), 0, stream>>>(
      projb, W2h_hi, W2h_lo, Wp_hi, Wp_lo, bp2, Woh2,
      b_h2h, w_score, bh, ctxi, xA, xB, cbuf, pp, hsb, bar);

  k_prep_wc<<<dim3(112), dim3(256), 0, stream>>>(W_cls, Wc_hi, Wc_lo);
  k4_cls<<<dim3(104), dim3(256), 0, stream>>>(hsb, Wc_hi, Wc_lo, b_cls, out);
}